// Round 2
// baseline (672.151 us; speedup 1.0000x reference)
//
#include <hip/hip_runtime.h>

// GaussianSampler: R[b,c] = sum_k X[b,c,k] * ws[c,k]
// B=32, C=1024, H=W=64, K=4096. mask is all-ones (identity gather) -> ignored.
//
// ws[c,k] = exp(-dx) * exp(-dy) / norm  (separable!)
//   dx = (xg[k]-wx[c])^2/(2 sx^2), dy likewise; norm = sqrt(2pi)*sx*sy*H*W/4
//   grid: xg[k] = -63/64 + (k & 63)/32,  yg[k] = -63/64 + (k >> 6)/32
//
// Memory-bound: 512 MB X streamed once -> ~81 us floor @ 6.3 TB/s achievable.
// Separability: per block only 64+64 exps into LDS tables (vs 4096 inline),
// streaming loop is 1 mul + 1 fma per element -> VALU fully hidden under HBM.
// One 256-thread block per (b,c), c fastest in blockIdx for contiguous stream.

#define NCH 1024
#define KDIM 4096   // 64*64

__global__ __launch_bounds__(256) void GaussianSampler_kernel(
    const float* __restrict__ X,
    const float* __restrict__ wx,
    const float* __restrict__ wy,
    const float* __restrict__ wsigmax,
    const float* __restrict__ wsigmay,
    float* __restrict__ out)
{
    const int bid = blockIdx.x;
    const int c   = bid & (NCH - 1);
    const int tid = threadIdx.x;

    __shared__ float ex[64];   // exp(-(xg-wx)^2 / 2sx^2)
    __shared__ float ey[64];   // exp(-(yg-wy)^2 / 2sy^2) * invnorm

    // Build separable tables: 128 exps per block instead of 4096.
    if (tid < 64) {
        const float sx   = wsigmax[c];
        const float i2sx = 0.5f / (sx * sx);
        const float tx   = (-0.984375f + 0.03125f * (float)tid) - wx[c];
        ex[tid] = __expf(-(tx * tx * i2sx));
    } else if (tid < 128) {
        const int   r    = tid - 64;
        const float sx   = wsigmax[c];
        const float sy   = wsigmay[c];
        const float i2sy = 0.5f / (sy * sy);
        // invnorm = 4 / (sqrt(2*pi) * sx * sy * 4096)
        const float invnorm = 4.0f / (2.5066282f * sx * sy * 4096.0f);
        const float ty   = (-0.984375f + 0.03125f * (float)r) - wy[c];
        ey[r] = __expf(-(ty * ty * i2sy)) * invnorm;
    }
    __syncthreads();

    const float4* __restrict__ Xp  = (const float4*)(X + (size_t)bid * KDIM);
    const float4* __restrict__ ex4 = (const float4*)ex;

    float acc = 0.0f;
    #pragma unroll
    for (int i = 0; i < 4; ++i) {
        const int k4 = tid + i * 256;        // float4 index, 0..1023
        const float4 v = Xp[k4];
        const int row  = k4 >> 4;            // (4*k4) >> 6
        const int col4 = k4 & 15;            // ((4*k4) & 63) / 4

        const float  eyr = ey[row];          // 4 distinct addrs / wave: broadcast
        const float4 e   = ex4[col4];        // 16 distinct b128 addrs: <=2-way, free

        acc += eyr * (v.x * e.x + v.y * e.y + v.z * e.z + v.w * e.w);
    }

    // Wave (64-lane) butterfly reduction
    #pragma unroll
    for (int off = 32; off > 0; off >>= 1)
        acc += __shfl_down(acc, off, 64);

    __shared__ float partial[4];
    const int lane = tid & 63;
    const int wave = tid >> 6;
    if (lane == 0) partial[wave] = acc;
    __syncthreads();
    if (tid == 0) {
        out[bid] = partial[0] + partial[1] + partial[2] + partial[3];
    }
}

extern "C" void kernel_launch(void* const* d_in, const int* in_sizes, int n_in,
                              void* d_out, int out_size, void* d_ws, size_t ws_size,
                              hipStream_t stream) {
    const float* X   = (const float*)d_in[0];
    const float* wx  = (const float*)d_in[1];
    const float* wy  = (const float*)d_in[2];
    const float* wsx = (const float*)d_in[3];
    const float* wsy = (const float*)d_in[4];
    // d_in[5] = mask: all-ones by construction -> identity gather, ignored.
    float* out = (float*)d_out;

    const int B = in_sizes[0] / (NCH * KDIM);   // 32
    dim3 grid(B * NCH);
    GaussianSampler_kernel<<<grid, 256, 0, stream>>>(X, wx, wy, wsx, wsy, out);
}